// Round 23
// baseline (47.635 us; speedup 1.0000x reference)
//
#include <hip/hip_runtime.h>
#include <hip/hip_fp16.h>

// out = x + softmax(x @ y^T) @ y ; B=8, S=2048, D=128, fp32 I/O, f16 MFMA (32x32x16).
// prepass: y -> yB f16 [B][SY][D] + yT f16 [B][D][SY]
// attn: swapped-QK^T flash attention, 8-wave blocks (QBLK=256), TWO 64-kv tiles
//       per barrier period over 4 LDS buffers (128 KB): { LOADT(2i+2); COMPUTE(2i);
//       STORET; LOADT(2i+3); COMPUTE(2i+1); STORET; barrier }. defer-rescale
//       (RTHR=4), per-group {8 exps -> cvt_pk -> permlane32_swap -> 4 PV MFMAs},
//       sums after PV. KV-split=4 f16 partials.
// combine: LSE merge + residual.
// [FINAL — stable best 47.57/47.62 us (R21/R22); R11 family baseline 47.82-48.65 us.
//  All lever families measured & closed: occupancy (R4/R6/R10/R13/R14/R17: 2 waves/
//  SIMD register/dispatcher bound), chain (R7/R9/R11), tiling (R6/R12/R21: barrier
//  ~2%), staging (R15), cross-tile pipeline (R19). Structural plateau; not claimed
//  as hardware roofline (MfmaUtil ~14%, VALUBusy ~28%, HBM ~15%).]

#define SX 2048
#define SY 2048
#define DD 128
#define KVBLK 64
#define NWAVE 8
#define QBLK (NWAVE * 32)     // 256
#define NTHREADS (NWAVE * 64) // 512
#define L2E 1.4426950408889634f
#define RTHR 4.0f

typedef __attribute__((ext_vector_type(8))) _Float16 f16x8;
typedef __attribute__((ext_vector_type(4))) _Float16 f16x4;
typedef __attribute__((ext_vector_type(4))) float f32x4;
typedef __attribute__((ext_vector_type(16))) float f32x16;
typedef __attribute__((ext_vector_type(4))) unsigned int u32x4;

// ---------------- prepass ----------------
template<bool WRITEB>
__global__ __launch_bounds__(256) void prepass(const float* __restrict__ y,
                                               _Float16* __restrict__ yB,
                                               _Float16* __restrict__ yT)
{
    __shared__ _Float16 T[64 * 64];
    char* Tb = (char*)T;
    const int tid = (int)threadIdx.x;
    const int b = blockIdx.y;
    const int k0 = (blockIdx.x >> 1) * 64;
    const int d0 = (blockIdx.x & 1) * 64;
    const float* yb = y + (size_t)b * SY * DD;
#pragma unroll
    for (int t = 0; t < 2; ++t) {
        int cid = t * 256 + tid;
        int row = cid >> 3, c = cid & 7;
        const float* gp = yb + (size_t)(k0 + row) * DD + d0 + c * 8;
        f32x4 a0 = *(const f32x4*)gp;
        f32x4 a1 = *(const f32x4*)(gp + 4);
        f16x8 v;
#pragma unroll
        for (int j = 0; j < 4; ++j) { v[j] = (_Float16)a0[j]; v[4 + j] = (_Float16)a1[j]; }
        if constexpr (WRITEB)
            *(f16x8*)(yB + ((size_t)b * SY + k0 + row) * DD + d0 + c * 8) = v;
        *(f16x8*)(Tb + ((row * 128 + c * 16) ^ ((row & 7) << 4))) = v;
    }
    __syncthreads();
#pragma unroll
    for (int t = 0; t < 2; ++t) {
        int cid = t * 256 + tid;
        int drow = cid >> 3, ck = cid & 7;
        f16x8 v;
#pragma unroll
        for (int j = 0; j < 8; ++j)
            v[j] = *(const _Float16*)(Tb + ((((ck * 8 + j) * 128) + drow * 2) ^ (j << 4)));
        *(f16x8*)(yT + ((size_t)b * DD + d0 + drow) * SY + k0 + ck * 8) = v;
    }
}

// ---------------- attention ----------------
// MODE: 2 = K from yB(f16) + V from yT ; 1 = K from y(f32) + V from yT ; 0 = all from y(f32)
template<bool SPLITOUT, int MODE>
__global__ __launch_bounds__(NTHREADS) void attn_fwd(
    const float* __restrict__ xg, const float* __restrict__ yg,
    const _Float16* __restrict__ yB, const _Float16* __restrict__ yT,
    float* __restrict__ og, _Float16* __restrict__ Opart,
    float* __restrict__ mpart, float* __restrict__ lpart,
    int kv_len, int nb)
{
    __shared__ __align__(16) unsigned char smem[4][32768];  // [buf][K 16KB | V^T 16KB]

    const int tid = (int)threadIdx.x;
    const int lane = tid & 63;
    const int wv = tid >> 6;
    const int l31 = lane & 31;
    const int hi = lane >> 5;
    const int swz = (l31 & 7) << 4;
    const int b = blockIdx.y;
    const int qbase = blockIdx.x * QBLK;
    const int sp = blockIdx.z;
    const int kv_begin = sp * kv_len;
    const int nt = kv_len / KVBLK;          // even in all dispatched configs

    const float* xb = xg + (size_t)b * SX * DD;
    const float* yb = yg + (size_t)b * SY * DD;

    // ---- Q fragments (B-operand): col = l31 -> qrow ; k = kst*16 + hi*8 + j ----
    const int qrow = qbase + wv * 32 + l31;
    f16x8 qreg[8];
#pragma unroll
    for (int kst = 0; kst < 8; ++kst) {
        const float* qp = xb + (size_t)qrow * DD + kst * 16 + hi * 8;
        f32x4 q0 = *(const f32x4*)qp;
        f32x4 q1 = *(const f32x4*)(qp + 4);
        f16x8 v;
#pragma unroll
        for (int j = 0; j < 4; ++j) { v[j] = (_Float16)q0[j]; v[4 + j] = (_Float16)q1[j]; }
        qreg[kst] = v;
    }

    // ---- staging registers (reused sequentially; live load->store only) ----
    f16x8 kh[2];     // MODE==2
    f32x4 kf[4];     // MODE<2
    f16x8 vh[2];     // MODE>=1

    auto LOADT = [&](int kv0) {
#pragma unroll
        for (int c = 0; c < 2; ++c) {
            int cid = c * NTHREADS + tid;
            int krow = cid >> 4, kc8 = cid & 15;
            if constexpr (MODE == 2) {
                kh[c] = *(const f16x8*)(yB + ((size_t)b * SY + kv0 + krow) * DD + kc8 * 8);
            } else {
                const float* gp = yb + (size_t)(kv0 + krow) * DD + kc8 * 8;
                kf[c * 2]     = *(const f32x4*)gp;
                kf[c * 2 + 1] = *(const f32x4*)(gp + 4);
            }
        }
        if constexpr (MODE >= 1) {
#pragma unroll
            for (int c = 0; c < 2; ++c) {
                int cid = c * NTHREADS + tid;
                int d = cid >> 3, kc = cid & 7;
                vh[c] = *(const f16x8*)(yT + ((size_t)b * DD + d) * SY + kv0 + kc * 8);
            }
        }
    };
    auto STORET = [&](char* Kb, char* Vb) {
#pragma unroll
        for (int c = 0; c < 2; ++c) {
            int cid = c * NTHREADS + tid;
            int krow = cid >> 4, kc8 = cid & 15;
            f16x8 kv;
            if constexpr (MODE == 2) {
                kv = kh[c];
            } else {
#pragma unroll
                for (int j = 0; j < 4; ++j) { kv[j] = (_Float16)kf[c * 2][j]; kv[4 + j] = (_Float16)kf[c * 2 + 1][j]; }
            }
            *(f16x8*)(Kb + ((krow * 256 + kc8 * 16) ^ ((krow & 7) << 4))) = kv;
            if constexpr (MODE == 0) {
#pragma unroll
                for (int j = 0; j < 8; ++j) {
                    int d = kc8 * 8 + j;
                    *(_Float16*)(Vb + ((d * 128 + krow * 2) ^ ((d & 7) << 4))) = kv[j];
                }
            }
        }
        if constexpr (MODE >= 1) {
#pragma unroll
            for (int c = 0; c < 2; ++c) {
                int cid = c * NTHREADS + tid;
                int d = cid >> 3, kc = cid & 7;
                *(f16x8*)(Vb + ((d * 128 + kc * 16) ^ ((d & 7) << 4))) = vh[c];
            }
        }
    };

    f32x16 o[4];
#pragma unroll
    for (int dt = 0; dt < 4; ++dt) o[dt] = f32x16{};
    float m = -3.0e38f, ls = 0.f;

    // ---- per-tile compute (R11 body verbatim, parameterized on buffer) ----
    auto COMPUTE = [&](char* Kb) {
        char* Vb = Kb + 16384;
        f32x16 sc[2];
        __builtin_amdgcn_s_setprio(1);
#pragma unroll
        for (int s = 0; s < 2; ++s) {
            f32x16 acc = f32x16{};
#pragma unroll
            for (int kst = 0; kst < 8; ++kst) {
                f16x8 kfr = *(const f16x8*)(Kb + (((32 * s + l31) * 256 + kst * 32 + hi * 16) ^ swz));
                acc = __builtin_amdgcn_mfma_f32_32x32x16_f16(kfr, qreg[kst], acc, 0, 0, 0);
            }
            sc[s] = acc;
        }
        __builtin_amdgcn_s_setprio(0);

        float tv[16];
#pragma unroll
        for (int r = 0; r < 16; ++r) tv[r] = fmaxf(sc[0][r], sc[1][r]);
#pragma unroll
        for (int st = 8; st >= 1; st >>= 1)
#pragma unroll
            for (int i = 0; i < 8; ++i)
                if (i < st) tv[i] = fmaxf(tv[i], tv[i + st]);
        float tm = tv[0];
        tm = fmaxf(tm, __shfl_xor(tm, 32, 64));
        if (!__all(tm <= m + RTHR)) {
            float mn = fmaxf(m, tm);
            float al = __builtin_exp2f((m - mn) * L2E);
            m = mn;
            ls *= al;
#pragma unroll
            for (int dt = 0; dt < 4; ++dt)
#pragma unroll
                for (int r = 0; r < 16; ++r) o[dt][r] *= al;
        }
        float mnl = m * L2E;

        float gsum[4];
#pragma unroll
        for (int s = 0; s < 2; ++s) {
#pragma unroll
            for (int k = 0; k < 2; ++k) {
                float p0 = __builtin_exp2f(__builtin_fmaf(sc[s][8 * k + 0], L2E, -mnl));
                float p1 = __builtin_exp2f(__builtin_fmaf(sc[s][8 * k + 1], L2E, -mnl));
                float p2 = __builtin_exp2f(__builtin_fmaf(sc[s][8 * k + 2], L2E, -mnl));
                float p3 = __builtin_exp2f(__builtin_fmaf(sc[s][8 * k + 3], L2E, -mnl));
                float p4 = __builtin_exp2f(__builtin_fmaf(sc[s][8 * k + 4], L2E, -mnl));
                float p5 = __builtin_exp2f(__builtin_fmaf(sc[s][8 * k + 5], L2E, -mnl));
                float p6 = __builtin_exp2f(__builtin_fmaf(sc[s][8 * k + 6], L2E, -mnl));
                float p7 = __builtin_exp2f(__builtin_fmaf(sc[s][8 * k + 7], L2E, -mnl));
                gsum[s * 2 + k] = ((p0 + p1) + (p2 + p3)) + ((p4 + p5) + (p6 + p7));
                unsigned aw = __builtin_bit_cast(unsigned, __builtin_amdgcn_cvt_pkrtz(p0, p1));
                unsigned cw = __builtin_bit_cast(unsigned, __builtin_amdgcn_cvt_pkrtz(p2, p3));
                unsigned bw = __builtin_bit_cast(unsigned, __builtin_amdgcn_cvt_pkrtz(p4, p5));
                unsigned dw = __builtin_bit_cast(unsigned, __builtin_amdgcn_cvt_pkrtz(p6, p7));
                asm("v_permlane32_swap_b32 %0, %1" : "+v"(aw), "+v"(bw));
                asm("v_permlane32_swap_b32 %0, %1" : "+v"(cw), "+v"(dw));
                u32x4 ww;
                ww[0] = aw;
                ww[1] = cw;
                ww[2] = bw;
                ww[3] = dw;
                f16x8 pf = __builtin_bit_cast(f16x8, ww);
                __builtin_amdgcn_s_setprio(1);
#pragma unroll
                for (int dt = 0; dt < 4; ++dt) {
                    f16x8 vf = *(const f16x8*)(Vb + (((dt * 32 + l31) * 128 + 64 * s + 32 * k + 16 * hi) ^ swz));
                    o[dt] = __builtin_amdgcn_mfma_f32_32x32x16_f16(vf, pf, o[dt], 0, 0, 0);
                }
                __builtin_amdgcn_s_setprio(0);
            }
        }
        float ps = (gsum[0] + gsum[1]) + (gsum[2] + gsum[3]);
        ps += __shfl_xor(ps, 32, 64);
        ls += ps;
    };

    // ---- prologue: stage tiles 0,1 into buffers 0,1 ----
    LOADT(kv_begin);
    STORET((char*)smem[0], (char*)smem[0] + 16384);
    if (nt > 1) {
        LOADT(kv_begin + KVBLK);
        STORET((char*)smem[1], (char*)smem[1] + 16384);
    }
    __syncthreads();

    // ---- main loop: TWO tiles per barrier; pairs alternate buffers {0,1} <-> {2,3} ----
    const int np = nt >> 1;
    for (int i = 0; i < np; ++i) {
        const int base = (i & 1) * 2;
        const int nbase = ((i + 1) & 1) * 2;
        const int ta = 2 * i, tb2 = 2 * i + 1;

        if (ta + 2 < nt) LOADT(kv_begin + (ta + 2) * KVBLK);   // lands under tile-a compute
        COMPUTE((char*)smem[base]);                             // tile 2i
        if (ta + 2 < nt) {
            char* Kn = (char*)smem[nbase];
            STORET(Kn, Kn + 16384);
        }

        if (tb2 + 2 < nt) LOADT(kv_begin + (tb2 + 2) * KVBLK); // lands under tile-b compute
        COMPUTE((char*)smem[base + 1]);                         // tile 2i+1
        if (tb2 + 2 < nt) {
            char* Kn = (char*)smem[nbase + 1];
            STORET(Kn, Kn + 16384);
        }

        __syncthreads();   // ONE barrier per pair: next pair staged & current pair released
    }

    // ---- epilogue: per-wave LDS transpose, coalesced stores ----
    float inv = SPLITOUT ? 1.0f : (1.0f / ls);
    if constexpr (SPLITOUT) {
        if (lane < 32) {
            size_t mi = ((size_t)sp * nb + b) * SX + qrow;
            mpart[mi] = m;
            lpart[mi] = ls;
        }
    }
    char* Ep = (char*)smem[0] + wv * 4096;   // per-wave [32 q][32 d] f32, swizzled
    for (int dt = 0; dt < 4; ++dt) {
#pragma unroll
        for (int g = 0; g < 4; ++g)
#pragma unroll
            for (int t4 = 0; t4 < 4; ++t4) {
                int r = g * 4 + t4;
                int dl = t4 + 8 * g + 4 * hi;
                *(float*)(Ep + (l31 * 128 + ((dl * 4) ^ swz))) = o[dt][r] * inv;
            }
        asm volatile("s_waitcnt lgkmcnt(0)" ::: "memory");
        if constexpr (SPLITOUT) {
            _Float16* Ob = Opart + ((size_t)sp * nb + b) * SX * DD;
#pragma unroll
            for (int i = 0; i < 2; ++i) {
                int id = i * 64 + lane;
                int q2 = id >> 2, c8 = id & 3;
                int qs = (q2 & 7) << 4;
                f32x4 e0 = *(const f32x4*)(Ep + (q2 * 128 + ((c8 * 32) ^ qs)));
                f32x4 e1 = *(const f32x4*)(Ep + (q2 * 128 + ((c8 * 32 + 16) ^ qs)));
                f16x8 h;
#pragma unroll
                for (int j = 0; j < 4; ++j) { h[j] = (_Float16)e0[j]; h[4 + j] = (_Float16)e1[j]; }
                *(f16x8*)(Ob + (size_t)(qbase + wv * 32 + q2) * DD + dt * 32 + c8 * 8) = h;
            }
        } else {
            float* ob = og + (size_t)b * SX * DD;
#pragma unroll
            for (int i = 0; i < 4; ++i) {
                int id = i * 64 + lane;
                int q2 = id >> 3, ch = id & 7;
                int qs = (q2 & 7) << 4;
                f32x4 e = *(const f32x4*)(Ep + (q2 * 128 + ((ch * 16) ^ qs)));
                size_t gi = (size_t)(qbase + wv * 32 + q2) * DD + dt * 32 + ch * 4;
                f32x4 xv = *(const f32x4*)(xb + gi);
                f32x4 rs;
#pragma unroll
                for (int j = 0; j < 4; ++j) rs[j] = xv[j] + e[j];
                *(f32x4*)(ob + gi) = rs;
            }
        }
        asm volatile("s_waitcnt lgkmcnt(0)" ::: "memory");
    }
}

// ---------------- combine ----------------
__global__ __launch_bounds__(256) void combine(const float* __restrict__ x,
    const _Float16* __restrict__ Opart, const float* __restrict__ mpart,
    const float* __restrict__ lpart, float* __restrict__ out, int nb, int nsplit)
{
    int tid = (int)threadIdx.x;
    int gr = blockIdx.x * 8 + (tid >> 5);
    int c = tid & 31;
    size_t nrows = (size_t)nb * SX;
    float M = -3.0e38f;
    for (int s = 0; s < nsplit; ++s) M = fmaxf(M, mpart[(size_t)s * nrows + gr]);
    float wsum = 0.f;
    float acc[4] = {0.f, 0.f, 0.f, 0.f};
    for (int s = 0; s < nsplit; ++s) {
        float ms = mpart[(size_t)s * nrows + gr];
        float lv = lpart[(size_t)s * nrows + gr];
        float wv = __builtin_exp2f((ms - M) * L2E);
        wsum += wv * lv;
        f16x4 h = *(const f16x4*)(Opart + (size_t)s * nrows * DD + (size_t)gr * DD + c * 4);
#pragma unroll
        for (int j = 0; j < 4; ++j) acc[j] += wv * (float)h[j];
    }
    float inv = 1.0f / wsum;
    size_t off = (size_t)gr * DD + c * 4;
    f32x4 xv = *(const f32x4*)(x + off);
    f32x4 rs;
#pragma unroll
    for (int j = 0; j < 4; ++j) rs[j] = xv[j] + acc[j] * inv;
    *(f32x4*)(out + off) = rs;
}

extern "C" void kernel_launch(void* const* d_in, const int* in_sizes, int n_in,
                              void* d_out, int out_size, void* d_ws, size_t ws_size,
                              hipStream_t stream) {
    const float* x = (const float*)d_in[0];
    const float* y = (const float*)d_in[1];
    float* out = (float*)d_out;
    int nb = in_sizes[0] / (SX * DD);

    size_t yBsz = (size_t)nb * SY * DD * sizeof(_Float16);
    size_t yTsz = yBsz;
    auto opsz = [&](int n) { return (size_t)n * nb * SX * DD * sizeof(_Float16); };
    auto mlsz = [&](int n) { return (size_t)n * nb * SX * sizeof(float); };
    char* w = (char*)d_ws;
    dim3 pgrid((SY / 64) * (DD / 64), nb);

    if (ws_size >= yBsz + yTsz + opsz(4) + 2 * mlsz(4)) {
        // MODE 2, nsplit 4
        _Float16* yB = (_Float16*)w;
        _Float16* yT = (_Float16*)(w + yBsz);
        _Float16* Op = (_Float16*)(w + yBsz + yTsz);
        float* mp = (float*)(w + yBsz + yTsz + opsz(4));
        float* lp = mp + (size_t)4 * nb * SX;
        prepass<true><<<pgrid, 256, 0, stream>>>(y, yB, yT);
        attn_fwd<true, 2><<<dim3(SX / QBLK, nb, 4), NTHREADS, 0, stream>>>(
            x, y, yB, yT, out, Op, mp, lp, SY / 4, nb);
        combine<<<dim3(nb * SX / 8), 256, 0, stream>>>(x, Op, mp, lp, out, nb, 4);
    } else if (ws_size >= yTsz + opsz(4) + 2 * mlsz(4)) {
        // MODE 1, nsplit 4
        _Float16* yT = (_Float16*)w;
        _Float16* Op = (_Float16*)(w + yTsz);
        float* mp = (float*)(w + yTsz + opsz(4));
        float* lp = mp + (size_t)4 * nb * SX;
        prepass<false><<<pgrid, 256, 0, stream>>>(y, nullptr, yT);
        attn_fwd<true, 1><<<dim3(SX / QBLK, nb, 4), NTHREADS, 0, stream>>>(
            x, y, nullptr, yT, out, Op, mp, lp, SY / 4, nb);
        combine<<<dim3(nb * SX / 8), 256, 0, stream>>>(x, Op, mp, lp, out, nb, 4);
    } else if (ws_size >= yTsz + opsz(2) + 2 * mlsz(2)) {
        // MODE 1, nsplit 2
        _Float16* yT = (_Float16*)w;
        _Float16* Op = (_Float16*)(w + yTsz);
        float* mp = (float*)(w + yTsz + opsz(2));
        float* lp = mp + (size_t)2 * nb * SX;
        prepass<false><<<pgrid, 256, 0, stream>>>(y, nullptr, yT);
        attn_fwd<true, 1><<<dim3(SX / QBLK, nb, 2), NTHREADS, 0, stream>>>(
            x, y, nullptr, yT, out, Op, mp, lp, SY / 2, nb);
        combine<<<dim3(nb * SX / 8), 256, 0, stream>>>(x, Op, mp, lp, out, nb, 2);
    } else if (ws_size >= yTsz) {
        // MODE 1, no split
        _Float16* yT = (_Float16*)w;
        prepass<false><<<pgrid, 256, 0, stream>>>(y, nullptr, yT);
        attn_fwd<false, 1><<<dim3(SX / QBLK, nb, 1), NTHREADS, 0, stream>>>(
            x, y, nullptr, yT, out, nullptr, nullptr, nullptr, SY, nb);
    } else {
        // MODE 0, no split
        attn_fwd<false, 0><<<dim3(SX / QBLK, nb, 1), NTHREADS, 0, stream>>>(
            x, y, nullptr, nullptr, out, nullptr, nullptr, nullptr, SY, nb);
    }
}

// Round 24
// 47.532 us; speedup vs baseline: 1.0022x; 1.0022x over previous
//
#include <hip/hip_runtime.h>
#include <hip/hip_fp16.h>

// out = x + softmax(x @ y^T) @ y ; B=8, S=2048, D=128, fp32 I/O, f16 MFMA (32x32x16).
// prepass: y -> yB f16 [B][SY][D] + yT f16 [B][D][SY]
// attn: swapped-QK^T flash attention, 8-wave blocks (QBLK=256), TWO 64-kv tiles
//       per barrier period over 4 LDS buffers (128 KB): { LOADT(2i+2); COMPUTE(2i);
//       STORET; LOADT(2i+3); COMPUTE(2i+1); STORET; barrier }. defer-rescale
//       (RTHR=4), per-group {8 exps -> cvt_pk -> permlane32_swap -> 4 PV MFMAs},
//       sums after PV. KV-split=4 f16 partials.
// combine: LSE merge + residual.
// [FINAL — converged: 47.57/47.62/47.63 us over three runs (R21/R22/R23);
//  R11 family baseline 47.82-48.65 us over four runs. All lever families
//  measured & closed. Structural plateau at 2 waves/SIMD; not claimed as
//  hardware roofline (MfmaUtil ~14%, VALUBusy ~28%, HBM ~15%).]

#define SX 2048
#define SY 2048
#define DD 128
#define KVBLK 64
#define NWAVE 8
#define QBLK (NWAVE * 32)     // 256
#define NTHREADS (NWAVE * 64) // 512
#define L2E 1.4426950408889634f
#define RTHR 4.0f

typedef __attribute__((ext_vector_type(8))) _Float16 f16x8;
typedef __attribute__((ext_vector_type(4))) _Float16 f16x4;
typedef __attribute__((ext_vector_type(4))) float f32x4;
typedef __attribute__((ext_vector_type(16))) float f32x16;
typedef __attribute__((ext_vector_type(4))) unsigned int u32x4;

// ---------------- prepass ----------------
template<bool WRITEB>
__global__ __launch_bounds__(256) void prepass(const float* __restrict__ y,
                                               _Float16* __restrict__ yB,
                                               _Float16* __restrict__ yT)
{
    __shared__ _Float16 T[64 * 64];
    char* Tb = (char*)T;
    const int tid = (int)threadIdx.x;
    const int b = blockIdx.y;
    const int k0 = (blockIdx.x >> 1) * 64;
    const int d0 = (blockIdx.x & 1) * 64;
    const float* yb = y + (size_t)b * SY * DD;
#pragma unroll
    for (int t = 0; t < 2; ++t) {
        int cid = t * 256 + tid;
        int row = cid >> 3, c = cid & 7;
        const float* gp = yb + (size_t)(k0 + row) * DD + d0 + c * 8;
        f32x4 a0 = *(const f32x4*)gp;
        f32x4 a1 = *(const f32x4*)(gp + 4);
        f16x8 v;
#pragma unroll
        for (int j = 0; j < 4; ++j) { v[j] = (_Float16)a0[j]; v[4 + j] = (_Float16)a1[j]; }
        if constexpr (WRITEB)
            *(f16x8*)(yB + ((size_t)b * SY + k0 + row) * DD + d0 + c * 8) = v;
        *(f16x8*)(Tb + ((row * 128 + c * 16) ^ ((row & 7) << 4))) = v;
    }
    __syncthreads();
#pragma unroll
    for (int t = 0; t < 2; ++t) {
        int cid = t * 256 + tid;
        int drow = cid >> 3, ck = cid & 7;
        f16x8 v;
#pragma unroll
        for (int j = 0; j < 8; ++j)
            v[j] = *(const _Float16*)(Tb + ((((ck * 8 + j) * 128) + drow * 2) ^ (j << 4)));
        *(f16x8*)(yT + ((size_t)b * DD + d0 + drow) * SY + k0 + ck * 8) = v;
    }
}

// ---------------- attention ----------------
// MODE: 2 = K from yB(f16) + V from yT ; 1 = K from y(f32) + V from yT ; 0 = all from y(f32)
template<bool SPLITOUT, int MODE>
__global__ __launch_bounds__(NTHREADS) void attn_fwd(
    const float* __restrict__ xg, const float* __restrict__ yg,
    const _Float16* __restrict__ yB, const _Float16* __restrict__ yT,
    float* __restrict__ og, _Float16* __restrict__ Opart,
    float* __restrict__ mpart, float* __restrict__ lpart,
    int kv_len, int nb)
{
    __shared__ __align__(16) unsigned char smem[4][32768];  // [buf][K 16KB | V^T 16KB]

    const int tid = (int)threadIdx.x;
    const int lane = tid & 63;
    const int wv = tid >> 6;
    const int l31 = lane & 31;
    const int hi = lane >> 5;
    const int swz = (l31 & 7) << 4;
    const int b = blockIdx.y;
    const int qbase = blockIdx.x * QBLK;
    const int sp = blockIdx.z;
    const int kv_begin = sp * kv_len;
    const int nt = kv_len / KVBLK;          // even in all dispatched configs

    const float* xb = xg + (size_t)b * SX * DD;
    const float* yb = yg + (size_t)b * SY * DD;

    // ---- Q fragments (B-operand): col = l31 -> qrow ; k = kst*16 + hi*8 + j ----
    const int qrow = qbase + wv * 32 + l31;
    f16x8 qreg[8];
#pragma unroll
    for (int kst = 0; kst < 8; ++kst) {
        const float* qp = xb + (size_t)qrow * DD + kst * 16 + hi * 8;
        f32x4 q0 = *(const f32x4*)qp;
        f32x4 q1 = *(const f32x4*)(qp + 4);
        f16x8 v;
#pragma unroll
        for (int j = 0; j < 4; ++j) { v[j] = (_Float16)q0[j]; v[4 + j] = (_Float16)q1[j]; }
        qreg[kst] = v;
    }

    // ---- staging registers (reused sequentially; live load->store only) ----
    f16x8 kh[2];     // MODE==2
    f32x4 kf[4];     // MODE<2
    f16x8 vh[2];     // MODE>=1

    auto LOADT = [&](int kv0) {
#pragma unroll
        for (int c = 0; c < 2; ++c) {
            int cid = c * NTHREADS + tid;
            int krow = cid >> 4, kc8 = cid & 15;
            if constexpr (MODE == 2) {
                kh[c] = *(const f16x8*)(yB + ((size_t)b * SY + kv0 + krow) * DD + kc8 * 8);
            } else {
                const float* gp = yb + (size_t)(kv0 + krow) * DD + kc8 * 8;
                kf[c * 2]     = *(const f32x4*)gp;
                kf[c * 2 + 1] = *(const f32x4*)(gp + 4);
            }
        }
        if constexpr (MODE >= 1) {
#pragma unroll
            for (int c = 0; c < 2; ++c) {
                int cid = c * NTHREADS + tid;
                int d = cid >> 3, kc = cid & 7;
                vh[c] = *(const f16x8*)(yT + ((size_t)b * DD + d) * SY + kv0 + kc * 8);
            }
        }
    };
    auto STORET = [&](char* Kb, char* Vb) {
#pragma unroll
        for (int c = 0; c < 2; ++c) {
            int cid = c * NTHREADS + tid;
            int krow = cid >> 4, kc8 = cid & 15;
            f16x8 kv;
            if constexpr (MODE == 2) {
                kv = kh[c];
            } else {
#pragma unroll
                for (int j = 0; j < 4; ++j) { kv[j] = (_Float16)kf[c * 2][j]; kv[4 + j] = (_Float16)kf[c * 2 + 1][j]; }
            }
            *(f16x8*)(Kb + ((krow * 256 + kc8 * 16) ^ ((krow & 7) << 4))) = kv;
            if constexpr (MODE == 0) {
#pragma unroll
                for (int j = 0; j < 8; ++j) {
                    int d = kc8 * 8 + j;
                    *(_Float16*)(Vb + ((d * 128 + krow * 2) ^ ((d & 7) << 4))) = kv[j];
                }
            }
        }
        if constexpr (MODE >= 1) {
#pragma unroll
            for (int c = 0; c < 2; ++c) {
                int cid = c * NTHREADS + tid;
                int d = cid >> 3, kc = cid & 7;
                *(f16x8*)(Vb + ((d * 128 + kc * 16) ^ ((d & 7) << 4))) = vh[c];
            }
        }
    };

    f32x16 o[4];
#pragma unroll
    for (int dt = 0; dt < 4; ++dt) o[dt] = f32x16{};
    float m = -3.0e38f, ls = 0.f;

    // ---- per-tile compute (R11 body verbatim, parameterized on buffer) ----
    auto COMPUTE = [&](char* Kb) {
        char* Vb = Kb + 16384;
        f32x16 sc[2];
        __builtin_amdgcn_s_setprio(1);
#pragma unroll
        for (int s = 0; s < 2; ++s) {
            f32x16 acc = f32x16{};
#pragma unroll
            for (int kst = 0; kst < 8; ++kst) {
                f16x8 kfr = *(const f16x8*)(Kb + (((32 * s + l31) * 256 + kst * 32 + hi * 16) ^ swz));
                acc = __builtin_amdgcn_mfma_f32_32x32x16_f16(kfr, qreg[kst], acc, 0, 0, 0);
            }
            sc[s] = acc;
        }
        __builtin_amdgcn_s_setprio(0);

        float tv[16];
#pragma unroll
        for (int r = 0; r < 16; ++r) tv[r] = fmaxf(sc[0][r], sc[1][r]);
#pragma unroll
        for (int st = 8; st >= 1; st >>= 1)
#pragma unroll
            for (int i = 0; i < 8; ++i)
                if (i < st) tv[i] = fmaxf(tv[i], tv[i + st]);
        float tm = tv[0];
        tm = fmaxf(tm, __shfl_xor(tm, 32, 64));
        if (!__all(tm <= m + RTHR)) {
            float mn = fmaxf(m, tm);
            float al = __builtin_exp2f((m - mn) * L2E);
            m = mn;
            ls *= al;
#pragma unroll
            for (int dt = 0; dt < 4; ++dt)
#pragma unroll
                for (int r = 0; r < 16; ++r) o[dt][r] *= al;
        }
        float mnl = m * L2E;

        float gsum[4];
#pragma unroll
        for (int s = 0; s < 2; ++s) {
#pragma unroll
            for (int k = 0; k < 2; ++k) {
                float p0 = __builtin_exp2f(__builtin_fmaf(sc[s][8 * k + 0], L2E, -mnl));
                float p1 = __builtin_exp2f(__builtin_fmaf(sc[s][8 * k + 1], L2E, -mnl));
                float p2 = __builtin_exp2f(__builtin_fmaf(sc[s][8 * k + 2], L2E, -mnl));
                float p3 = __builtin_exp2f(__builtin_fmaf(sc[s][8 * k + 3], L2E, -mnl));
                float p4 = __builtin_exp2f(__builtin_fmaf(sc[s][8 * k + 4], L2E, -mnl));
                float p5 = __builtin_exp2f(__builtin_fmaf(sc[s][8 * k + 5], L2E, -mnl));
                float p6 = __builtin_exp2f(__builtin_fmaf(sc[s][8 * k + 6], L2E, -mnl));
                float p7 = __builtin_exp2f(__builtin_fmaf(sc[s][8 * k + 7], L2E, -mnl));
                gsum[s * 2 + k] = ((p0 + p1) + (p2 + p3)) + ((p4 + p5) + (p6 + p7));
                unsigned aw = __builtin_bit_cast(unsigned, __builtin_amdgcn_cvt_pkrtz(p0, p1));
                unsigned cw = __builtin_bit_cast(unsigned, __builtin_amdgcn_cvt_pkrtz(p2, p3));
                unsigned bw = __builtin_bit_cast(unsigned, __builtin_amdgcn_cvt_pkrtz(p4, p5));
                unsigned dw = __builtin_bit_cast(unsigned, __builtin_amdgcn_cvt_pkrtz(p6, p7));
                asm("v_permlane32_swap_b32 %0, %1" : "+v"(aw), "+v"(bw));
                asm("v_permlane32_swap_b32 %0, %1" : "+v"(cw), "+v"(dw));
                u32x4 ww;
                ww[0] = aw;
                ww[1] = cw;
                ww[2] = bw;
                ww[3] = dw;
                f16x8 pf = __builtin_bit_cast(f16x8, ww);
                __builtin_amdgcn_s_setprio(1);
#pragma unroll
                for (int dt = 0; dt < 4; ++dt) {
                    f16x8 vf = *(const f16x8*)(Vb + (((dt * 32 + l31) * 128 + 64 * s + 32 * k + 16 * hi) ^ swz));
                    o[dt] = __builtin_amdgcn_mfma_f32_32x32x16_f16(vf, pf, o[dt], 0, 0, 0);
                }
                __builtin_amdgcn_s_setprio(0);
            }
        }
        float ps = (gsum[0] + gsum[1]) + (gsum[2] + gsum[3]);
        ps += __shfl_xor(ps, 32, 64);
        ls += ps;
    };

    // ---- prologue: stage tiles 0,1 into buffers 0,1 ----
    LOADT(kv_begin);
    STORET((char*)smem[0], (char*)smem[0] + 16384);
    if (nt > 1) {
        LOADT(kv_begin + KVBLK);
        STORET((char*)smem[1], (char*)smem[1] + 16384);
    }
    __syncthreads();

    // ---- main loop: TWO tiles per barrier; pairs alternate buffers {0,1} <-> {2,3} ----
    const int np = nt >> 1;
    for (int i = 0; i < np; ++i) {
        const int base = (i & 1) * 2;
        const int nbase = ((i + 1) & 1) * 2;
        const int ta = 2 * i, tb2 = 2 * i + 1;

        if (ta + 2 < nt) LOADT(kv_begin + (ta + 2) * KVBLK);   // lands under tile-a compute
        COMPUTE((char*)smem[base]);                             // tile 2i
        if (ta + 2 < nt) {
            char* Kn = (char*)smem[nbase];
            STORET(Kn, Kn + 16384);
        }

        if (tb2 + 2 < nt) LOADT(kv_begin + (tb2 + 2) * KVBLK); // lands under tile-b compute
        COMPUTE((char*)smem[base + 1]);                         // tile 2i+1
        if (tb2 + 2 < nt) {
            char* Kn = (char*)smem[nbase + 1];
            STORET(Kn, Kn + 16384);
        }

        __syncthreads();   // ONE barrier per pair: next pair staged & current pair released
    }

    // ---- epilogue: per-wave LDS transpose, coalesced stores ----
    float inv = SPLITOUT ? 1.0f : (1.0f / ls);
    if constexpr (SPLITOUT) {
        if (lane < 32) {
            size_t mi = ((size_t)sp * nb + b) * SX + qrow;
            mpart[mi] = m;
            lpart[mi] = ls;
        }
    }
    char* Ep = (char*)smem[0] + wv * 4096;   // per-wave [32 q][32 d] f32, swizzled
    for (int dt = 0; dt < 4; ++dt) {
#pragma unroll
        for (int g = 0; g < 4; ++g)
#pragma unroll
            for (int t4 = 0; t4 < 4; ++t4) {
                int r = g * 4 + t4;
                int dl = t4 + 8 * g + 4 * hi;
                *(float*)(Ep + (l31 * 128 + ((dl * 4) ^ swz))) = o[dt][r] * inv;
            }
        asm volatile("s_waitcnt lgkmcnt(0)" ::: "memory");
        if constexpr (SPLITOUT) {
            _Float16* Ob = Opart + ((size_t)sp * nb + b) * SX * DD;
#pragma unroll
            for (int i = 0; i < 2; ++i) {
                int id = i * 64 + lane;
                int q2 = id >> 2, c8 = id & 3;
                int qs = (q2 & 7) << 4;
                f32x4 e0 = *(const f32x4*)(Ep + (q2 * 128 + ((c8 * 32) ^ qs)));
                f32x4 e1 = *(const f32x4*)(Ep + (q2 * 128 + ((c8 * 32 + 16) ^ qs)));
                f16x8 h;
#pragma unroll
                for (int j = 0; j < 4; ++j) { h[j] = (_Float16)e0[j]; h[4 + j] = (_Float16)e1[j]; }
                *(f16x8*)(Ob + (size_t)(qbase + wv * 32 + q2) * DD + dt * 32 + c8 * 8) = h;
            }
        } else {
            float* ob = og + (size_t)b * SX * DD;
#pragma unroll
            for (int i = 0; i < 4; ++i) {
                int id = i * 64 + lane;
                int q2 = id >> 3, ch = id & 7;
                int qs = (q2 & 7) << 4;
                f32x4 e = *(const f32x4*)(Ep + (q2 * 128 + ((ch * 16) ^ qs)));
                size_t gi = (size_t)(qbase + wv * 32 + q2) * DD + dt * 32 + ch * 4;
                f32x4 xv = *(const f32x4*)(xb + gi);
                f32x4 rs;
#pragma unroll
                for (int j = 0; j < 4; ++j) rs[j] = xv[j] + e[j];
                *(f32x4*)(ob + gi) = rs;
            }
        }
        asm volatile("s_waitcnt lgkmcnt(0)" ::: "memory");
    }
}

// ---------------- combine ----------------
__global__ __launch_bounds__(256) void combine(const float* __restrict__ x,
    const _Float16* __restrict__ Opart, const float* __restrict__ mpart,
    const float* __restrict__ lpart, float* __restrict__ out, int nb, int nsplit)
{
    int tid = (int)threadIdx.x;
    int gr = blockIdx.x * 8 + (tid >> 5);
    int c = tid & 31;
    size_t nrows = (size_t)nb * SX;
    float M = -3.0e38f;
    for (int s = 0; s < nsplit; ++s) M = fmaxf(M, mpart[(size_t)s * nrows + gr]);
    float wsum = 0.f;
    float acc[4] = {0.f, 0.f, 0.f, 0.f};
    for (int s = 0; s < nsplit; ++s) {
        float ms = mpart[(size_t)s * nrows + gr];
        float lv = lpart[(size_t)s * nrows + gr];
        float wv = __builtin_exp2f((ms - M) * L2E);
        wsum += wv * lv;
        f16x4 h = *(const f16x4*)(Opart + (size_t)s * nrows * DD + (size_t)gr * DD + c * 4);
#pragma unroll
        for (int j = 0; j < 4; ++j) acc[j] += wv * (float)h[j];
    }
    float inv = 1.0f / wsum;
    size_t off = (size_t)gr * DD + c * 4;
    f32x4 xv = *(const f32x4*)(x + off);
    f32x4 rs;
#pragma unroll
    for (int j = 0; j < 4; ++j) rs[j] = xv[j] + acc[j] * inv;
    *(f32x4*)(out + off) = rs;
}

extern "C" void kernel_launch(void* const* d_in, const int* in_sizes, int n_in,
                              void* d_out, int out_size, void* d_ws, size_t ws_size,
                              hipStream_t stream) {
    const float* x = (const float*)d_in[0];
    const float* y = (const float*)d_in[1];
    float* out = (float*)d_out;
    int nb = in_sizes[0] / (SX * DD);

    size_t yBsz = (size_t)nb * SY * DD * sizeof(_Float16);
    size_t yTsz = yBsz;
    auto opsz = [&](int n) { return (size_t)n * nb * SX * DD * sizeof(_Float16); };
    auto mlsz = [&](int n) { return (size_t)n * nb * SX * sizeof(float); };
    char* w = (char*)d_ws;
    dim3 pgrid((SY / 64) * (DD / 64), nb);

    if (ws_size >= yBsz + yTsz + opsz(4) + 2 * mlsz(4)) {
        // MODE 2, nsplit 4
        _Float16* yB = (_Float16*)w;
        _Float16* yT = (_Float16*)(w + yBsz);
        _Float16* Op = (_Float16*)(w + yBsz + yTsz);
        float* mp = (float*)(w + yBsz + yTsz + opsz(4));
        float* lp = mp + (size_t)4 * nb * SX;
        prepass<true><<<pgrid, 256, 0, stream>>>(y, yB, yT);
        attn_fwd<true, 2><<<dim3(SX / QBLK, nb, 4), NTHREADS, 0, stream>>>(
            x, y, yB, yT, out, Op, mp, lp, SY / 4, nb);
        combine<<<dim3(nb * SX / 8), 256, 0, stream>>>(x, Op, mp, lp, out, nb, 4);
    } else if (ws_size >= yTsz + opsz(4) + 2 * mlsz(4)) {
        // MODE 1, nsplit 4
        _Float16* yT = (_Float16*)w;
        _Float16* Op = (_Float16*)(w + yTsz);
        float* mp = (float*)(w + yTsz + opsz(4));
        float* lp = mp + (size_t)4 * nb * SX;
        prepass<false><<<pgrid, 256, 0, stream>>>(y, nullptr, yT);
        attn_fwd<true, 1><<<dim3(SX / QBLK, nb, 4), NTHREADS, 0, stream>>>(
            x, y, nullptr, yT, out, Op, mp, lp, SY / 4, nb);
        combine<<<dim3(nb * SX / 8), 256, 0, stream>>>(x, Op, mp, lp, out, nb, 4);
    } else if (ws_size >= yTsz + opsz(2) + 2 * mlsz(2)) {
        // MODE 1, nsplit 2
        _Float16* yT = (_Float16*)w;
        _Float16* Op = (_Float16*)(w + yTsz);
        float* mp = (float*)(w + yTsz + opsz(2));
        float* lp = mp + (size_t)2 * nb * SX;
        prepass<false><<<pgrid, 256, 0, stream>>>(y, nullptr, yT);
        attn_fwd<true, 1><<<dim3(SX / QBLK, nb, 2), NTHREADS, 0, stream>>>(
            x, y, nullptr, yT, out, Op, mp, lp, SY / 2, nb);
        combine<<<dim3(nb * SX / 8), 256, 0, stream>>>(x, Op, mp, lp, out, nb, 2);
    } else if (ws_size >= yTsz) {
        // MODE 1, no split
        _Float16* yT = (_Float16*)w;
        prepass<false><<<pgrid, 256, 0, stream>>>(y, nullptr, yT);
        attn_fwd<false, 1><<<dim3(SX / QBLK, nb, 1), NTHREADS, 0, stream>>>(
            x, y, nullptr, yT, out, nullptr, nullptr, nullptr, SY, nb);
    } else {
        // MODE 0, no split
        attn_fwd<false, 0><<<dim3(SX / QBLK, nb, 1), NTHREADS, 0, stream>>>(
            x, y, nullptr, nullptr, out, nullptr, nullptr, nullptr, SY, nb);
    }
}

// Round 25
// 47.397 us; speedup vs baseline: 1.0050x; 1.0028x over previous
//
#include <hip/hip_runtime.h>
#include <hip/hip_fp16.h>

// out = x + softmax(x @ y^T) @ y ; B=8, S=2048, D=128, fp32 I/O, f16 MFMA (32x32x16).
// prepass: y -> yB f16 [B][SY][D] + yT f16 [B][D][SY]
// attn: swapped-QK^T flash attention, 8-wave blocks (QBLK=256), TWO 64-kv tiles
//       per barrier period over 4 LDS buffers (128 KB): { LOADT(2i+2); COMPUTE(2i);
//       STORET; LOADT(2i+3); COMPUTE(2i+1); STORET; barrier }. defer-rescale
//       (RTHR=4), per-group {8 exps -> cvt_pk -> permlane32_swap -> 4 PV MFMAs},
//       sums after PV. KV-split=4 f16 partials.
// combine: LSE merge + residual.
// [FINAL — converged: 47.53-47.63 us over four runs (R21-R24). All lever
//  families measured & closed. Structural plateau at 2 waves/SIMD; not
//  claimed as hardware roofline (MfmaUtil ~14%, VALUBusy ~27%, HBM ~15%).]

#define SX 2048
#define SY 2048
#define DD 128
#define KVBLK 64
#define NWAVE 8
#define QBLK (NWAVE * 32)     // 256
#define NTHREADS (NWAVE * 64) // 512
#define L2E 1.4426950408889634f
#define RTHR 4.0f

typedef __attribute__((ext_vector_type(8))) _Float16 f16x8;
typedef __attribute__((ext_vector_type(4))) _Float16 f16x4;
typedef __attribute__((ext_vector_type(4))) float f32x4;
typedef __attribute__((ext_vector_type(16))) float f32x16;
typedef __attribute__((ext_vector_type(4))) unsigned int u32x4;

// ---------------- prepass ----------------
template<bool WRITEB>
__global__ __launch_bounds__(256) void prepass(const float* __restrict__ y,
                                               _Float16* __restrict__ yB,
                                               _Float16* __restrict__ yT)
{
    __shared__ _Float16 T[64 * 64];
    char* Tb = (char*)T;
    const int tid = (int)threadIdx.x;
    const int b = blockIdx.y;
    const int k0 = (blockIdx.x >> 1) * 64;
    const int d0 = (blockIdx.x & 1) * 64;
    const float* yb = y + (size_t)b * SY * DD;
#pragma unroll
    for (int t = 0; t < 2; ++t) {
        int cid = t * 256 + tid;
        int row = cid >> 3, c = cid & 7;
        const float* gp = yb + (size_t)(k0 + row) * DD + d0 + c * 8;
        f32x4 a0 = *(const f32x4*)gp;
        f32x4 a1 = *(const f32x4*)(gp + 4);
        f16x8 v;
#pragma unroll
        for (int j = 0; j < 4; ++j) { v[j] = (_Float16)a0[j]; v[4 + j] = (_Float16)a1[j]; }
        if constexpr (WRITEB)
            *(f16x8*)(yB + ((size_t)b * SY + k0 + row) * DD + d0 + c * 8) = v;
        *(f16x8*)(Tb + ((row * 128 + c * 16) ^ ((row & 7) << 4))) = v;
    }
    __syncthreads();
#pragma unroll
    for (int t = 0; t < 2; ++t) {
        int cid = t * 256 + tid;
        int drow = cid >> 3, ck = cid & 7;
        f16x8 v;
#pragma unroll
        for (int j = 0; j < 8; ++j)
            v[j] = *(const _Float16*)(Tb + ((((ck * 8 + j) * 128) + drow * 2) ^ (j << 4)));
        *(f16x8*)(yT + ((size_t)b * DD + d0 + drow) * SY + k0 + ck * 8) = v;
    }
}

// ---------------- attention ----------------
// MODE: 2 = K from yB(f16) + V from yT ; 1 = K from y(f32) + V from yT ; 0 = all from y(f32)
template<bool SPLITOUT, int MODE>
__global__ __launch_bounds__(NTHREADS) void attn_fwd(
    const float* __restrict__ xg, const float* __restrict__ yg,
    const _Float16* __restrict__ yB, const _Float16* __restrict__ yT,
    float* __restrict__ og, _Float16* __restrict__ Opart,
    float* __restrict__ mpart, float* __restrict__ lpart,
    int kv_len, int nb)
{
    __shared__ __align__(16) unsigned char smem[4][32768];  // [buf][K 16KB | V^T 16KB]

    const int tid = (int)threadIdx.x;
    const int lane = tid & 63;
    const int wv = tid >> 6;
    const int l31 = lane & 31;
    const int hi = lane >> 5;
    const int swz = (l31 & 7) << 4;
    const int b = blockIdx.y;
    const int qbase = blockIdx.x * QBLK;
    const int sp = blockIdx.z;
    const int kv_begin = sp * kv_len;
    const int nt = kv_len / KVBLK;          // even in all dispatched configs

    const float* xb = xg + (size_t)b * SX * DD;
    const float* yb = yg + (size_t)b * SY * DD;

    // ---- Q fragments (B-operand): col = l31 -> qrow ; k = kst*16 + hi*8 + j ----
    const int qrow = qbase + wv * 32 + l31;
    f16x8 qreg[8];
#pragma unroll
    for (int kst = 0; kst < 8; ++kst) {
        const float* qp = xb + (size_t)qrow * DD + kst * 16 + hi * 8;
        f32x4 q0 = *(const f32x4*)qp;
        f32x4 q1 = *(const f32x4*)(qp + 4);
        f16x8 v;
#pragma unroll
        for (int j = 0; j < 4; ++j) { v[j] = (_Float16)q0[j]; v[4 + j] = (_Float16)q1[j]; }
        qreg[kst] = v;
    }

    // ---- staging registers (reused sequentially; live load->store only) ----
    f16x8 kh[2];     // MODE==2
    f32x4 kf[4];     // MODE<2
    f16x8 vh[2];     // MODE>=1

    auto LOADT = [&](int kv0) {
#pragma unroll
        for (int c = 0; c < 2; ++c) {
            int cid = c * NTHREADS + tid;
            int krow = cid >> 4, kc8 = cid & 15;
            if constexpr (MODE == 2) {
                kh[c] = *(const f16x8*)(yB + ((size_t)b * SY + kv0 + krow) * DD + kc8 * 8);
            } else {
                const float* gp = yb + (size_t)(kv0 + krow) * DD + kc8 * 8;
                kf[c * 2]     = *(const f32x4*)gp;
                kf[c * 2 + 1] = *(const f32x4*)(gp + 4);
            }
        }
        if constexpr (MODE >= 1) {
#pragma unroll
            for (int c = 0; c < 2; ++c) {
                int cid = c * NTHREADS + tid;
                int d = cid >> 3, kc = cid & 7;
                vh[c] = *(const f16x8*)(yT + ((size_t)b * DD + d) * SY + kv0 + kc * 8);
            }
        }
    };
    auto STORET = [&](char* Kb, char* Vb) {
#pragma unroll
        for (int c = 0; c < 2; ++c) {
            int cid = c * NTHREADS + tid;
            int krow = cid >> 4, kc8 = cid & 15;
            f16x8 kv;
            if constexpr (MODE == 2) {
                kv = kh[c];
            } else {
#pragma unroll
                for (int j = 0; j < 4; ++j) { kv[j] = (_Float16)kf[c * 2][j]; kv[4 + j] = (_Float16)kf[c * 2 + 1][j]; }
            }
            *(f16x8*)(Kb + ((krow * 256 + kc8 * 16) ^ ((krow & 7) << 4))) = kv;
            if constexpr (MODE == 0) {
#pragma unroll
                for (int j = 0; j < 8; ++j) {
                    int d = kc8 * 8 + j;
                    *(_Float16*)(Vb + ((d * 128 + krow * 2) ^ ((d & 7) << 4))) = kv[j];
                }
            }
        }
        if constexpr (MODE >= 1) {
#pragma unroll
            for (int c = 0; c < 2; ++c) {
                int cid = c * NTHREADS + tid;
                int d = cid >> 3, kc = cid & 7;
                *(f16x8*)(Vb + ((d * 128 + kc * 16) ^ ((d & 7) << 4))) = vh[c];
            }
        }
    };

    f32x16 o[4];
#pragma unroll
    for (int dt = 0; dt < 4; ++dt) o[dt] = f32x16{};
    float m = -3.0e38f, ls = 0.f;

    // ---- per-tile compute (R11 body verbatim, parameterized on buffer) ----
    auto COMPUTE = [&](char* Kb) {
        char* Vb = Kb + 16384;
        f32x16 sc[2];
        __builtin_amdgcn_s_setprio(1);
#pragma unroll
        for (int s = 0; s < 2; ++s) {
            f32x16 acc = f32x16{};
#pragma unroll
            for (int kst = 0; kst < 8; ++kst) {
                f16x8 kfr = *(const f16x8*)(Kb + (((32 * s + l31) * 256 + kst * 32 + hi * 16) ^ swz));
                acc = __builtin_amdgcn_mfma_f32_32x32x16_f16(kfr, qreg[kst], acc, 0, 0, 0);
            }
            sc[s] = acc;
        }
        __builtin_amdgcn_s_setprio(0);

        float tv[16];
#pragma unroll
        for (int r = 0; r < 16; ++r) tv[r] = fmaxf(sc[0][r], sc[1][r]);
#pragma unroll
        for (int st = 8; st >= 1; st >>= 1)
#pragma unroll
            for (int i = 0; i < 8; ++i)
                if (i < st) tv[i] = fmaxf(tv[i], tv[i + st]);
        float tm = tv[0];
        tm = fmaxf(tm, __shfl_xor(tm, 32, 64));
        if (!__all(tm <= m + RTHR)) {
            float mn = fmaxf(m, tm);
            float al = __builtin_exp2f((m - mn) * L2E);
            m = mn;
            ls *= al;
#pragma unroll
            for (int dt = 0; dt < 4; ++dt)
#pragma unroll
                for (int r = 0; r < 16; ++r) o[dt][r] *= al;
        }
        float mnl = m * L2E;

        float gsum[4];
#pragma unroll
        for (int s = 0; s < 2; ++s) {
#pragma unroll
            for (int k = 0; k < 2; ++k) {
                float p0 = __builtin_exp2f(__builtin_fmaf(sc[s][8 * k + 0], L2E, -mnl));
                float p1 = __builtin_exp2f(__builtin_fmaf(sc[s][8 * k + 1], L2E, -mnl));
                float p2 = __builtin_exp2f(__builtin_fmaf(sc[s][8 * k + 2], L2E, -mnl));
                float p3 = __builtin_exp2f(__builtin_fmaf(sc[s][8 * k + 3], L2E, -mnl));
                float p4 = __builtin_exp2f(__builtin_fmaf(sc[s][8 * k + 4], L2E, -mnl));
                float p5 = __builtin_exp2f(__builtin_fmaf(sc[s][8 * k + 5], L2E, -mnl));
                float p6 = __builtin_exp2f(__builtin_fmaf(sc[s][8 * k + 6], L2E, -mnl));
                float p7 = __builtin_exp2f(__builtin_fmaf(sc[s][8 * k + 7], L2E, -mnl));
                gsum[s * 2 + k] = ((p0 + p1) + (p2 + p3)) + ((p4 + p5) + (p6 + p7));
                unsigned aw = __builtin_bit_cast(unsigned, __builtin_amdgcn_cvt_pkrtz(p0, p1));
                unsigned cw = __builtin_bit_cast(unsigned, __builtin_amdgcn_cvt_pkrtz(p2, p3));
                unsigned bw = __builtin_bit_cast(unsigned, __builtin_amdgcn_cvt_pkrtz(p4, p5));
                unsigned dw = __builtin_bit_cast(unsigned, __builtin_amdgcn_cvt_pkrtz(p6, p7));
                asm("v_permlane32_swap_b32 %0, %1" : "+v"(aw), "+v"(bw));
                asm("v_permlane32_swap_b32 %0, %1" : "+v"(cw), "+v"(dw));
                u32x4 ww;
                ww[0] = aw;
                ww[1] = cw;
                ww[2] = bw;
                ww[3] = dw;
                f16x8 pf = __builtin_bit_cast(f16x8, ww);
                __builtin_amdgcn_s_setprio(1);
#pragma unroll
                for (int dt = 0; dt < 4; ++dt) {
                    f16x8 vf = *(const f16x8*)(Vb + (((dt * 32 + l31) * 128 + 64 * s + 32 * k + 16 * hi) ^ swz));
                    o[dt] = __builtin_amdgcn_mfma_f32_32x32x16_f16(vf, pf, o[dt], 0, 0, 0);
                }
                __builtin_amdgcn_s_setprio(0);
            }
        }
        float ps = (gsum[0] + gsum[1]) + (gsum[2] + gsum[3]);
        ps += __shfl_xor(ps, 32, 64);
        ls += ps;
    };

    // ---- prologue: stage tiles 0,1 into buffers 0,1 ----
    LOADT(kv_begin);
    STORET((char*)smem[0], (char*)smem[0] + 16384);
    if (nt > 1) {
        LOADT(kv_begin + KVBLK);
        STORET((char*)smem[1], (char*)smem[1] + 16384);
    }
    __syncthreads();

    // ---- main loop: TWO tiles per barrier; pairs alternate buffers {0,1} <-> {2,3} ----
    const int np = nt >> 1;
    for (int i = 0; i < np; ++i) {
        const int base = (i & 1) * 2;
        const int nbase = ((i + 1) & 1) * 2;
        const int ta = 2 * i, tb2 = 2 * i + 1;

        if (ta + 2 < nt) LOADT(kv_begin + (ta + 2) * KVBLK);   // lands under tile-a compute
        COMPUTE((char*)smem[base]);                             // tile 2i
        if (ta + 2 < nt) {
            char* Kn = (char*)smem[nbase];
            STORET(Kn, Kn + 16384);
        }

        if (tb2 + 2 < nt) LOADT(kv_begin + (tb2 + 2) * KVBLK); // lands under tile-b compute
        COMPUTE((char*)smem[base + 1]);                         // tile 2i+1
        if (tb2 + 2 < nt) {
            char* Kn = (char*)smem[nbase + 1];
            STORET(Kn, Kn + 16384);
        }

        __syncthreads();   // ONE barrier per pair: next pair staged & current pair released
    }

    // ---- epilogue: per-wave LDS transpose, coalesced stores ----
    float inv = SPLITOUT ? 1.0f : (1.0f / ls);
    if constexpr (SPLITOUT) {
        if (lane < 32) {
            size_t mi = ((size_t)sp * nb + b) * SX + qrow;
            mpart[mi] = m;
            lpart[mi] = ls;
        }
    }
    char* Ep = (char*)smem[0] + wv * 4096;   // per-wave [32 q][32 d] f32, swizzled
    for (int dt = 0; dt < 4; ++dt) {
#pragma unroll
        for (int g = 0; g < 4; ++g)
#pragma unroll
            for (int t4 = 0; t4 < 4; ++t4) {
                int r = g * 4 + t4;
                int dl = t4 + 8 * g + 4 * hi;
                *(float*)(Ep + (l31 * 128 + ((dl * 4) ^ swz))) = o[dt][r] * inv;
            }
        asm volatile("s_waitcnt lgkmcnt(0)" ::: "memory");
        if constexpr (SPLITOUT) {
            _Float16* Ob = Opart + ((size_t)sp * nb + b) * SX * DD;
#pragma unroll
            for (int i = 0; i < 2; ++i) {
                int id = i * 64 + lane;
                int q2 = id >> 2, c8 = id & 3;
                int qs = (q2 & 7) << 4;
                f32x4 e0 = *(const f32x4*)(Ep + (q2 * 128 + ((c8 * 32) ^ qs)));
                f32x4 e1 = *(const f32x4*)(Ep + (q2 * 128 + ((c8 * 32 + 16) ^ qs)));
                f16x8 h;
#pragma unroll
                for (int j = 0; j < 4; ++j) { h[j] = (_Float16)e0[j]; h[4 + j] = (_Float16)e1[j]; }
                *(f16x8*)(Ob + (size_t)(qbase + wv * 32 + q2) * DD + dt * 32 + c8 * 8) = h;
            }
        } else {
            float* ob = og + (size_t)b * SX * DD;
#pragma unroll
            for (int i = 0; i < 4; ++i) {
                int id = i * 64 + lane;
                int q2 = id >> 3, ch = id & 7;
                int qs = (q2 & 7) << 4;
                f32x4 e = *(const f32x4*)(Ep + (q2 * 128 + ((ch * 16) ^ qs)));
                size_t gi = (size_t)(qbase + wv * 32 + q2) * DD + dt * 32 + ch * 4;
                f32x4 xv = *(const f32x4*)(xb + gi);
                f32x4 rs;
#pragma unroll
                for (int j = 0; j < 4; ++j) rs[j] = xv[j] + e[j];
                *(f32x4*)(ob + gi) = rs;
            }
        }
        asm volatile("s_waitcnt lgkmcnt(0)" ::: "memory");
    }
}

// ---------------- combine ----------------
__global__ __launch_bounds__(256) void combine(const float* __restrict__ x,
    const _Float16* __restrict__ Opart, const float* __restrict__ mpart,
    const float* __restrict__ lpart, float* __restrict__ out, int nb, int nsplit)
{
    int tid = (int)threadIdx.x;
    int gr = blockIdx.x * 8 + (tid >> 5);
    int c = tid & 31;
    size_t nrows = (size_t)nb * SX;
    float M = -3.0e38f;
    for (int s = 0; s < nsplit; ++s) M = fmaxf(M, mpart[(size_t)s * nrows + gr]);
    float wsum = 0.f;
    float acc[4] = {0.f, 0.f, 0.f, 0.f};
    for (int s = 0; s < nsplit; ++s) {
        float ms = mpart[(size_t)s * nrows + gr];
        float lv = lpart[(size_t)s * nrows + gr];
        float wv = __builtin_exp2f((ms - M) * L2E);
        wsum += wv * lv;
        f16x4 h = *(const f16x4*)(Opart + (size_t)s * nrows * DD + (size_t)gr * DD + c * 4);
#pragma unroll
        for (int j = 0; j < 4; ++j) acc[j] += wv * (float)h[j];
    }
    float inv = 1.0f / wsum;
    size_t off = (size_t)gr * DD + c * 4;
    f32x4 xv = *(const f32x4*)(x + off);
    f32x4 rs;
#pragma unroll
    for (int j = 0; j < 4; ++j) rs[j] = xv[j] + acc[j] * inv;
    *(f32x4*)(out + off) = rs;
}

extern "C" void kernel_launch(void* const* d_in, const int* in_sizes, int n_in,
                              void* d_out, int out_size, void* d_ws, size_t ws_size,
                              hipStream_t stream) {
    const float* x = (const float*)d_in[0];
    const float* y = (const float*)d_in[1];
    float* out = (float*)d_out;
    int nb = in_sizes[0] / (SX * DD);

    size_t yBsz = (size_t)nb * SY * DD * sizeof(_Float16);
    size_t yTsz = yBsz;
    auto opsz = [&](int n) { return (size_t)n * nb * SX * DD * sizeof(_Float16); };
    auto mlsz = [&](int n) { return (size_t)n * nb * SX * sizeof(float); };
    char* w = (char*)d_ws;
    dim3 pgrid((SY / 64) * (DD / 64), nb);

    if (ws_size >= yBsz + yTsz + opsz(4) + 2 * mlsz(4)) {
        // MODE 2, nsplit 4
        _Float16* yB = (_Float16*)w;
        _Float16* yT = (_Float16*)(w + yBsz);
        _Float16* Op = (_Float16*)(w + yBsz + yTsz);
        float* mp = (float*)(w + yBsz + yTsz + opsz(4));
        float* lp = mp + (size_t)4 * nb * SX;
        prepass<true><<<pgrid, 256, 0, stream>>>(y, yB, yT);
        attn_fwd<true, 2><<<dim3(SX / QBLK, nb, 4), NTHREADS, 0, stream>>>(
            x, y, yB, yT, out, Op, mp, lp, SY / 4, nb);
        combine<<<dim3(nb * SX / 8), 256, 0, stream>>>(x, Op, mp, lp, out, nb, 4);
    } else if (ws_size >= yTsz + opsz(4) + 2 * mlsz(4)) {
        // MODE 1, nsplit 4
        _Float16* yT = (_Float16*)w;
        _Float16* Op = (_Float16*)(w + yTsz);
        float* mp = (float*)(w + yTsz + opsz(4));
        float* lp = mp + (size_t)4 * nb * SX;
        prepass<false><<<pgrid, 256, 0, stream>>>(y, nullptr, yT);
        attn_fwd<true, 1><<<dim3(SX / QBLK, nb, 4), NTHREADS, 0, stream>>>(
            x, y, nullptr, yT, out, Op, mp, lp, SY / 4, nb);
        combine<<<dim3(nb * SX / 8), 256, 0, stream>>>(x, Op, mp, lp, out, nb, 4);
    } else if (ws_size >= yTsz + opsz(2) + 2 * mlsz(2)) {
        // MODE 1, nsplit 2
        _Float16* yT = (_Float16*)w;
        _Float16* Op = (_Float16*)(w + yTsz);
        float* mp = (float*)(w + yTsz + opsz(2));
        float* lp = mp + (size_t)2 * nb * SX;
        prepass<false><<<pgrid, 256, 0, stream>>>(y, nullptr, yT);
        attn_fwd<true, 1><<<dim3(SX / QBLK, nb, 2), NTHREADS, 0, stream>>>(
            x, y, nullptr, yT, out, Op, mp, lp, SY / 2, nb);
        combine<<<dim3(nb * SX / 8), 256, 0, stream>>>(x, Op, mp, lp, out, nb, 2);
    } else if (ws_size >= yTsz) {
        // MODE 1, no split
        _Float16* yT = (_Float16*)w;
        prepass<false><<<pgrid, 256, 0, stream>>>(y, nullptr, yT);
        attn_fwd<false, 1><<<dim3(SX / QBLK, nb, 1), NTHREADS, 0, stream>>>(
            x, y, nullptr, yT, out, nullptr, nullptr, nullptr, SY, nb);
    } else {
        // MODE 0, no split
        attn_fwd<false, 0><<<dim3(SX / QBLK, nb, 1), NTHREADS, 0, stream>>>(
            x, y, nullptr, nullptr, out, nullptr, nullptr, nullptr, SY, nb);
    }
}